// Round 2
// baseline (378.508 us; speedup 1.0000x reference)
//
#include <hip/hip_runtime.h>

// SyntacticGCN on MI355X — dtype-adaptive (detects bf16 vs fp32 input buffers
// at runtime from b_in_gate == ones: bf16(1.0) low ushort = 0x3F80, fp32 = 0x0000).
// Pipeline:
//   detect -> convert inp/weights to canonical bf16 -> CSR-by-target build ->
//   XV GEMM (MFMA bf16) -> gate logits -> per-node gather/aggregate + residual + relu.

typedef __attribute__((ext_vector_type(8))) short short8;
typedef __attribute__((ext_vector_type(4))) float floatx4;
typedef __attribute__((ext_vector_type(4))) unsigned short ushort4v;

#define DIM 128

static __device__ __forceinline__ float bf2f(unsigned int u16bits) {
    unsigned int x = u16bits << 16;
    return __builtin_bit_cast(float, x);
}
static __device__ __forceinline__ unsigned short f2bf(float f) {
    unsigned int x = __builtin_bit_cast(unsigned int, f);
    unsigned int r = (x + 0x7fffu + ((x >> 16) & 1u)) >> 16;
    return (unsigned short)r;
}

// ---------------- dtype detect: flag=1 -> buffers are bf16; flag=0 -> fp32 --------
__global__ void detect_k(const unsigned short* __restrict__ bg_in, int* __restrict__ flag) {
    if (threadIdx.x == 0 && blockIdx.x == 0)
        *flag = (bg_in[0] == 0x3F80u) ? 1 : 0;
}

// ---------------- normalize a float tensor to canonical bf16 ----------------------
__global__ __launch_bounds__(256) void conv_k(const void* __restrict__ src,
                                              unsigned short* __restrict__ dst,
                                              const int* __restrict__ flag, int n4) {
    int i = blockIdx.x * 256 + threadIdx.x;
    if (i >= n4) return;
    if (*flag) {
        ((ushort4v*)dst)[i] = ((const ushort4v*)src)[i];
    } else {
        float4 v = ((const float4*)src)[i];
        ushort4v o;
        o[0] = f2bf(v.x); o[1] = f2bf(v.y); o[2] = f2bf(v.z); o[3] = f2bf(v.w);
        ((ushort4v*)dst)[i] = o;
    }
}

// ---------------- GEMM: XV[n][br*128+c] = sum_k xb[n][k] * wb[br][k][c] -----------
// 512 threads = 8 waves. wave -> (branch = wave>>1, col-half = wave&1).
// Operand swap: A = W fragment (M = output col), B = x fragment (N = node).
// D layout (16x16x32): node = lane&15, col = (lane>>4)*4 + reg -> packed 8B stores.
__global__ __launch_bounds__(512) void gemm_xv_k(
    const unsigned short* __restrict__ xb, const unsigned short* __restrict__ wb,
    unsigned short* __restrict__ xv, int ntiles, int N)
{
    int tid  = threadIdx.x;
    int wave = tid >> 6, lane = tid & 63;
    int br   = wave >> 1, half = wave & 1;
    int quad = lane >> 4, l15 = lane & 15;

    const unsigned short* W = wb + br * (DIM * DIM);

    short8 wf[4][4];
#pragma unroll
    for (int ct = 0; ct < 4; ++ct) {
        int c = half * 64 + ct * 16 + l15;
#pragma unroll
        for (int kt = 0; kt < 4; ++kt) {
            int k0 = kt * 32 + quad * 8;
            short8 f;
#pragma unroll
            for (int j = 0; j < 8; ++j)
                f[j] = (short)W[(k0 + j) * DIM + c];
            wf[ct][kt] = f;
        }
    }

    for (int tile = blockIdx.x; tile < ntiles; tile += gridDim.x) {
        int row0 = tile * 16;
        int row  = row0 + l15;
        int rowc = row < N ? row : N - 1;

        floatx4 acc[4];
#pragma unroll
        for (int ct = 0; ct < 4; ++ct) acc[ct] = (floatx4){0.f, 0.f, 0.f, 0.f};

#pragma unroll
        for (int kt = 0; kt < 4; ++kt) {
            short8 xf = *(const short8*)(xb + (size_t)rowc * DIM + kt * 32 + quad * 8);
#pragma unroll
            for (int ct = 0; ct < 4; ++ct)
                acc[ct] = __builtin_amdgcn_mfma_f32_16x16x32_bf16(wf[ct][kt], xf, acc[ct], 0, 0, 0);
        }

        if (row < N) {
#pragma unroll
            for (int ct = 0; ct < 4; ++ct) {
                int c = half * 64 + ct * 16 + quad * 4;
                ushort4v o;
#pragma unroll
                for (int r = 0; r < 4; ++r) o[r] = f2bf(acc[ct][r]);
                *(ushort4v*)(xv + (size_t)row * 512 + br * 128 + c) = o;
            }
        }
    }
}

// ---------------- Gate logits: XG[n][t] = sum_k xb[n][k] * gb[t][k] (fp32) --------
__global__ __launch_bounds__(256) void gate_xg_k(
    const unsigned short* __restrict__ xb, const unsigned short* __restrict__ gb,
    float* __restrict__ xg, int N)
{
    int n = blockIdx.x * 4 + (threadIdx.x >> 6);
    if (n >= N) return;
    int lane = threadIdx.x & 63;

    unsigned int x2 = *(const unsigned int*)(xb + (size_t)n * DIM + lane * 2);
    float x0 = bf2f(x2 & 0xffffu), x1 = bf2f(x2 >> 16);

    float s[4];
#pragma unroll
    for (int t = 0; t < 4; ++t) {
        unsigned int g2 = *(const unsigned int*)(gb + t * DIM + lane * 2);
        s[t] = x0 * bf2f(g2 & 0xffffu) + x1 * bf2f(g2 >> 16);
    }
#pragma unroll
    for (int off = 1; off < 64; off <<= 1) {
#pragma unroll
        for (int t = 0; t < 4; ++t) s[t] += __shfl_xor(s[t], off, 64);
    }
    if (lane == 0) *(float4*)(xg + (size_t)n * 4) = make_float4(s[0], s[1], s[2], s[3]);
}

// ---------------- CSR build by target ----------------
__global__ void hist_k(const int* __restrict__ ei, int* __restrict__ counts, int E) {
    int e = blockIdx.x * 256 + threadIdx.x;
    if (e < E) atomicAdd(&counts[ei[E + e]], 1);
}

__global__ __launch_bounds__(256) void scan_block_k(
    const int* __restrict__ counts, int* __restrict__ row_start,
    int* __restrict__ blocksums, int n)
{
    __shared__ int sdata[256];
    int tid = threadIdx.x;
    int base = blockIdx.x * 1024 + tid * 4;
    int v[4]; int s = 0;
#pragma unroll
    for (int j = 0; j < 4; ++j) {
        v[j] = (base + j < n) ? counts[base + j] : 0;
        s += v[j];
    }
    sdata[tid] = s;
    __syncthreads();
    for (int off = 1; off < 256; off <<= 1) {
        int t = (tid >= off) ? sdata[tid - off] : 0;
        __syncthreads();
        sdata[tid] += t;
        __syncthreads();
    }
    int run = sdata[tid] - s;
#pragma unroll
    for (int j = 0; j < 4; ++j) {
        if (base + j < n) row_start[base + j] = run;
        run += v[j];
    }
    if (tid == 255) blocksums[blockIdx.x] = sdata[255];
}

__global__ __launch_bounds__(128) void scan_sums_k(int* __restrict__ blocksums, int nb) {
    __shared__ int sdata[128];
    int tid = threadIdx.x;
    int v = (tid < nb) ? blocksums[tid] : 0;
    sdata[tid] = v;
    __syncthreads();
    for (int off = 1; off < 128; off <<= 1) {
        int t = (tid >= off) ? sdata[tid - off] : 0;
        __syncthreads();
        sdata[tid] += t;
        __syncthreads();
    }
    blocksums[tid] = sdata[tid] - v;
}

__global__ __launch_bounds__(256) void scan_add_k(
    int* __restrict__ row_start, int* __restrict__ cursor,
    const int* __restrict__ blocksums, int n)
{
    int off = blocksums[blockIdx.x];
    int base = blockIdx.x * 1024 + threadIdx.x * 4;
#pragma unroll
    for (int j = 0; j < 4; ++j) {
        int idx = base + j;
        if (idx < n) {
            int v = row_start[idx] + off;
            row_start[idx] = v;
            cursor[idx] = v;
        }
    }
}

__global__ void scatter_k(const int* __restrict__ ei, int* __restrict__ cursor,
                          int* __restrict__ edge_list, int E) {
    int e = blockIdx.x * 256 + threadIdx.x;
    if (e < E) {
        int pos = atomicAdd(&cursor[ei[E + e]], 1);
        edge_list[pos] = e;
    }
}

// ---------------- Aggregate: one wave per node, fused +inp and ReLU ---------------
__global__ __launch_bounds__(256) void aggregate_k(
    const unsigned short* __restrict__ xv, const float* __restrict__ xg,
    const int* __restrict__ row_start, const int* __restrict__ counts,
    const int* __restrict__ edge_list,
    const int* __restrict__ ei, const int* __restrict__ deprel,
    const int* __restrict__ deparc,
    const void* __restrict__ b_in, const void* __restrict__ b_out,
    const void* __restrict__ bg_in, const void* __restrict__ bg_out,
    const unsigned short* __restrict__ xb, void* __restrict__ out,
    const int* __restrict__ flag, int N)
{
    int n = blockIdx.x * 4 + (threadIdx.x >> 6);
    if (n >= N) return;
    int lane = threadIdx.x & 63;
    int isbf = *flag;

    float a0 = 0.f, a1 = 0.f;
    int start = row_start[n];
    int cnt   = counts[n];

    for (int i = 0; i < cnt; ++i) {
        int e   = edge_list[start + i];
        int t   = deparc[e];
        int src = ei[e];
        int rel = deprel[e];

        float gl = xg[(size_t)src * 4 + t];
        float b0 = 0.f, b1 = 0.f;
        if (t < 2) {
            const void* bp  = (t == 0) ? b_in  : b_out;
            const void* bgp = (t == 0) ? bg_in : bg_out;
            if (isbf) {
                gl += bf2f(((const unsigned short*)bgp)[rel]);
                unsigned int bb = *(const unsigned int*)((const unsigned short*)bp + (size_t)rel * DIM + lane * 2);
                b0 = bf2f(bb & 0xffffu); b1 = bf2f(bb >> 16);
            } else {
                gl += ((const float*)bgp)[rel];
                float2 bb = *(const float2*)((const float*)bp + (size_t)rel * DIM + lane * 2);
                b0 = bb.x; b1 = bb.y;
            }
        }
        float gate = 1.f / (1.f + __expf(-gl));

        unsigned int xx = *(const unsigned int*)(xv + (size_t)src * 512 + t * 128 + lane * 2);
        a0 += (bf2f(xx & 0xffffu) + b0) * gate;
        a1 += (bf2f(xx >> 16)     + b1) * gate;
    }

    unsigned int ix = *(const unsigned int*)(xb + (size_t)n * DIM + lane * 2);
    float o0 = fmaxf(a0 + bf2f(ix & 0xffffu), 0.f);
    float o1 = fmaxf(a1 + bf2f(ix >> 16), 0.f);
    if (isbf) {
        unsigned int o = (unsigned int)f2bf(o0) | ((unsigned int)f2bf(o1) << 16);
        *(unsigned int*)((unsigned short*)out + (size_t)n * DIM + lane * 2) = o;
    } else {
        *(float2*)((float*)out + (size_t)n * DIM + lane * 2) = make_float2(o0, o1);
    }
}

extern "C" void kernel_launch(void* const* d_in, const int* in_sizes, int n_in,
                              void* d_out, int out_size, void* d_ws, size_t ws_size,
                              hipStream_t stream)
{
    const void* inp    = d_in[0];
    const int*  deprel = (const int*)d_in[1];
    const int*  deparc = (const int*)d_in[2];
    const int*  ei     = (const int*)d_in[3];
    const void* Vin    = d_in[4];
    const void* b_in   = d_in[5];
    const void* gin    = d_in[6];
    const void* bg_in  = d_in[7];
    const void* Vout   = d_in[8];
    const void* b_out  = d_in[9];
    const void* gout   = d_in[10];
    const void* bg_out = d_in[11];
    const void* Wself  = d_in[12];
    const void* gself  = d_in[13];
    const void* Wnorel = d_in[14];
    const void* gnorel = d_in[15];

    const int N = in_sizes[0] / DIM;   // 100000
    const int E = in_sizes[1];         // 400000

    // workspace carve-out (256B aligned); small/critical arrays first
    char* ws = (char*)d_ws;
    size_t off = 0;
    auto alloc = [&](size_t bytes) -> void* {
        void* p = ws + off;
        off = (off + bytes + 255) & ~(size_t)255;
        return p;
    };
    int*            flag      = (int*)alloc(256);
    float*          xg        = (float*)alloc((size_t)N * 4 * 4);
    int*            counts    = (int*)alloc((size_t)N * 4);
    int*            row_start = (int*)alloc((size_t)N * 4);
    int*            cursor    = (int*)alloc((size_t)N * 4);
    int*            edge_list = (int*)alloc((size_t)E * 4);
    int*            blocksums = (int*)alloc(128 * 4);
    unsigned short* wb        = (unsigned short*)alloc((size_t)4 * DIM * DIM * 2);
    unsigned short* gb        = (unsigned short*)alloc((size_t)4 * DIM * 2);
    unsigned short* xb        = (unsigned short*)alloc((size_t)N * DIM * 2);  // 25.6 MB
    unsigned short* xv        = (unsigned short*)alloc((size_t)N * 512 * 2);  // 102.4 MB

    int nb_scan = (N + 1023) / 1024;
    int ntiles  = (N + 15) / 16;
    int nb_edge = (E + 255) / 256;
    int nb_node = (N + 3) / 4;
    int n4_inp  = N * DIM / 4;
    int n4_mat  = DIM * DIM / 4;
    int n4_vec  = DIM / 4;

    // dtype detect
    detect_k<<<1, 64, 0, stream>>>((const unsigned short*)bg_in, flag);

    // canonical bf16 copies
    conv_k<<<(n4_inp + 255) / 256, 256, 0, stream>>>(inp, xb, flag, n4_inp);
    conv_k<<<(n4_mat + 255) / 256, 256, 0, stream>>>(Vin,    wb + 0 * DIM * DIM, flag, n4_mat);
    conv_k<<<(n4_mat + 255) / 256, 256, 0, stream>>>(Vout,   wb + 1 * DIM * DIM, flag, n4_mat);
    conv_k<<<(n4_mat + 255) / 256, 256, 0, stream>>>(Wself,  wb + 2 * DIM * DIM, flag, n4_mat);
    conv_k<<<(n4_mat + 255) / 256, 256, 0, stream>>>(Wnorel, wb + 3 * DIM * DIM, flag, n4_mat);
    conv_k<<<1, 256, 0, stream>>>(gin,    gb + 0 * DIM, flag, n4_vec);
    conv_k<<<1, 256, 0, stream>>>(gout,   gb + 1 * DIM, flag, n4_vec);
    conv_k<<<1, 256, 0, stream>>>(gself,  gb + 2 * DIM, flag, n4_vec);
    conv_k<<<1, 256, 0, stream>>>(gnorel, gb + 3 * DIM, flag, n4_vec);

    // CSR build
    hipMemsetAsync(counts, 0, (size_t)N * 4, stream);
    hist_k<<<nb_edge, 256, 0, stream>>>(ei, counts, E);
    scan_block_k<<<nb_scan, 256, 0, stream>>>(counts, row_start, blocksums, N);
    scan_sums_k<<<1, 128, 0, stream>>>(blocksums, nb_scan);
    scan_add_k<<<nb_scan, 256, 0, stream>>>(row_start, cursor, blocksums, N);
    scatter_k<<<nb_edge, 256, 0, stream>>>(ei, cursor, edge_list, E);

    // dense transforms
    gemm_xv_k<<<640, 512, 0, stream>>>(xb, wb, xv, ntiles, N);
    gate_xg_k<<<nb_node, 256, 0, stream>>>(xb, gb, xg, N);

    // gather + gated accumulate + residual + relu
    aggregate_k<<<nb_node, 256, 0, stream>>>(xv, xg, row_start, counts, edge_list,
                                             ei, deprel, deparc, b_in, b_out,
                                             bg_in, bg_out, xb, d_out, flag, N);
}

// Round 3
// 318.648 us; speedup vs baseline: 1.1879x; 1.1879x over previous
//
#include <hip/hip_runtime.h>

// SyntacticGCN on MI355X — fp32 in/out (confirmed R2: WRITE_SIZE == N*128*4).
// Pipeline:
//   CSR-by-target build (hist/scan/scatter)
//   conv_gate_k : inp fp32 -> xb bf16 + gate logits xg fp32      (one pass)
//   gemm_xv_k   : XV[n][4*128] = xb @ {Vin,Vout,Wself,Wnorel}    (MFMA bf16)
//   payload_gate_k : per CSR position, packed (src,t,rel) + sigmoid gate
//   aggregate_k : per-node wave; parallel metadata + prefetched row gathers,
//                 fused bias add, residual, relu, fp32 store.

typedef __attribute__((ext_vector_type(8))) short short8;
typedef __attribute__((ext_vector_type(4))) float floatx4;
typedef __attribute__((ext_vector_type(4))) unsigned short ushort4v;

#define DIM 128

static __device__ __forceinline__ float bf2f(unsigned int u16bits) {
    unsigned int x = u16bits << 16;
    return __builtin_bit_cast(float, x);
}
static __device__ __forceinline__ unsigned int f2bf(float f) {
    unsigned int x = __builtin_bit_cast(unsigned int, f);
    return (x + 0x7fffu + ((x >> 16) & 1u)) >> 16;
}

// ---------------- fused: xb = bf16(inp), xg[n][t] = inp[n] . gate_t (fp32) --------
__global__ __launch_bounds__(256) void conv_gate_k(
    const float* __restrict__ inp,
    const float* __restrict__ gin,  const float* __restrict__ gout,
    const float* __restrict__ gself, const float* __restrict__ gnorel,
    unsigned short* __restrict__ xb, float* __restrict__ xg, int N)
{
    int n = blockIdx.x * 4 + (threadIdx.x >> 6);
    if (n >= N) return;
    int lane = threadIdx.x & 63;

    float2 x = *(const float2*)(inp + (size_t)n * DIM + lane * 2);
    unsigned int o = f2bf(x.x) | (f2bf(x.y) << 16);
    *(unsigned int*)(xb + (size_t)n * DIM + lane * 2) = o;

    float2 g0 = *(const float2*)(gin    + lane * 2);
    float2 g1 = *(const float2*)(gout   + lane * 2);
    float2 g2 = *(const float2*)(gself  + lane * 2);
    float2 g3 = *(const float2*)(gnorel + lane * 2);
    float s0 = x.x * g0.x + x.y * g0.y;
    float s1 = x.x * g1.x + x.y * g1.y;
    float s2 = x.x * g2.x + x.y * g2.y;
    float s3 = x.x * g3.x + x.y * g3.y;
#pragma unroll
    for (int off = 1; off < 64; off <<= 1) {
        s0 += __shfl_xor(s0, off, 64);
        s1 += __shfl_xor(s1, off, 64);
        s2 += __shfl_xor(s2, off, 64);
        s3 += __shfl_xor(s3, off, 64);
    }
    if (lane == 0) *(float4*)(xg + (size_t)n * 4) = make_float4(s0, s1, s2, s3);
}

// ---------------- GEMM: xv[n][br*128+c] = sum_k xb[n][k] * W_br[k][c] -------------
// 512 threads = 8 waves: wave -> (branch = wave>>1, col-half = wave&1).
// Operand swap: A = W fragment (M = output col), B = x fragment (N = node).
// D layout (16x16x32): node = lane&15, col = (lane>>4)*4 + reg -> packed 8B stores.
static __device__ __forceinline__ void load_xfrag(
    const unsigned short* __restrict__ xb, int tile, int l15, int quad, int N,
    short8 xf[4])
{
    int row = tile * 16 + l15;
    row = row < N ? row : N - 1;
#pragma unroll
    for (int kt = 0; kt < 4; ++kt)
        xf[kt] = *(const short8*)(xb + (size_t)row * DIM + kt * 32 + quad * 8);
}

__global__ __launch_bounds__(512) void gemm_xv_k(
    const unsigned short* __restrict__ xb,
    const float* __restrict__ W0, const float* __restrict__ W1,
    const float* __restrict__ W2, const float* __restrict__ W3,
    unsigned short* __restrict__ xv, int ntiles, int N)
{
    int tid  = threadIdx.x;
    int wave = tid >> 6, lane = tid & 63;
    int br   = wave >> 1, half = wave & 1;
    int quad = lane >> 4, l15 = lane & 15;

    const float* W = (br == 0) ? W0 : (br == 1) ? W1 : (br == 2) ? W2 : W3;

    // weight fragments, converted fp32 -> bf16 in-register (once per block)
    short8 wf[4][4];
#pragma unroll
    for (int ct = 0; ct < 4; ++ct) {
        int c = half * 64 + ct * 16 + l15;
#pragma unroll
        for (int kt = 0; kt < 4; ++kt) {
            int k0 = kt * 32 + quad * 8;
            short8 f;
#pragma unroll
            for (int j = 0; j < 8; ++j)
                f[j] = (short)f2bf(W[(size_t)(k0 + j) * DIM + c]);
            wf[ct][kt] = f;
        }
    }

    int tile = blockIdx.x;
    if (tile >= ntiles) return;

    short8 xf[4];
    load_xfrag(xb, tile, l15, quad, N, xf);

    while (true) {
        int next = tile + gridDim.x;
        short8 xf2[4];
        if (next < ntiles) load_xfrag(xb, next, l15, quad, N, xf2);  // prefetch

        floatx4 acc[4];
#pragma unroll
        for (int ct = 0; ct < 4; ++ct) acc[ct] = (floatx4){0.f, 0.f, 0.f, 0.f};
#pragma unroll
        for (int kt = 0; kt < 4; ++kt)
#pragma unroll
            for (int ct = 0; ct < 4; ++ct)
                acc[ct] = __builtin_amdgcn_mfma_f32_16x16x32_bf16(wf[ct][kt], xf[kt], acc[ct], 0, 0, 0);

        int row = tile * 16 + l15;
        if (row < N) {
#pragma unroll
            for (int ct = 0; ct < 4; ++ct) {
                int c = half * 64 + ct * 16 + quad * 4;
                ushort4v o;
#pragma unroll
                for (int r = 0; r < 4; ++r) o[r] = (unsigned short)f2bf(acc[ct][r]);
                *(ushort4v*)(xv + (size_t)row * 512 + br * 128 + c) = o;
            }
        }
        if (next >= ntiles) break;
        tile = next;
#pragma unroll
        for (int kt = 0; kt < 4; ++kt) xf[kt] = xf2[kt];
    }
}

// ---------------- CSR build by target ----------------
__global__ void hist_k(const int* __restrict__ ei, int* __restrict__ counts, int E) {
    int e = blockIdx.x * 256 + threadIdx.x;
    if (e < E) atomicAdd(&counts[ei[E + e]], 1);
}

__global__ __launch_bounds__(256) void scan_block_k(
    const int* __restrict__ counts, int* __restrict__ row_start,
    int* __restrict__ blocksums, int n)
{
    __shared__ int sdata[256];
    int tid = threadIdx.x;
    int base = blockIdx.x * 1024 + tid * 4;
    int v[4]; int s = 0;
#pragma unroll
    for (int j = 0; j < 4; ++j) {
        v[j] = (base + j < n) ? counts[base + j] : 0;
        s += v[j];
    }
    sdata[tid] = s;
    __syncthreads();
    for (int off = 1; off < 256; off <<= 1) {
        int t = (tid >= off) ? sdata[tid - off] : 0;
        __syncthreads();
        sdata[tid] += t;
        __syncthreads();
    }
    int run = sdata[tid] - s;
#pragma unroll
    for (int j = 0; j < 4; ++j) {
        if (base + j < n) row_start[base + j] = run;
        run += v[j];
    }
    if (tid == 255) blocksums[blockIdx.x] = sdata[255];
}

__global__ __launch_bounds__(128) void scan_sums_k(int* __restrict__ blocksums, int nb) {
    __shared__ int sdata[128];
    int tid = threadIdx.x;
    int v = (tid < nb) ? blocksums[tid] : 0;
    sdata[tid] = v;
    __syncthreads();
    for (int off = 1; off < 128; off <<= 1) {
        int t = (tid >= off) ? sdata[tid - off] : 0;
        __syncthreads();
        sdata[tid] += t;
        __syncthreads();
    }
    blocksums[tid] = sdata[tid] - v;
}

__global__ __launch_bounds__(256) void scan_add_k(
    int* __restrict__ row_start, int* __restrict__ cursor,
    const int* __restrict__ blocksums, int n)
{
    int off = blocksums[blockIdx.x];
    int base = blockIdx.x * 1024 + threadIdx.x * 4;
#pragma unroll
    for (int j = 0; j < 4; ++j) {
        int idx = base + j;
        if (idx < n) {
            int v = row_start[idx] + off;
            row_start[idx] = v;
            cursor[idx] = v;
        }
    }
}

__global__ void scatter_k(const int* __restrict__ ei, int* __restrict__ cursor,
                          int* __restrict__ edge_list, int E) {
    int e = blockIdx.x * 256 + threadIdx.x;
    if (e < E) {
        int pos = atomicAdd(&cursor[ei[E + e]], 1);
        edge_list[pos] = e;
    }
}

// ---------------- per CSR position: packed payload + precomputed sigmoid gate -----
// All random reads here hit L2-resident tables (ei/deprel/deparc 1.6 MB each,
// xg 1.6 MB, bg_* 1.6 MB each). Writes coalesced.
__global__ __launch_bounds__(256) void payload_gate_k(
    const int* __restrict__ edge_list,
    const int* __restrict__ ei, const int* __restrict__ deprel,
    const int* __restrict__ deparc,
    const float* __restrict__ xg,
    const float* __restrict__ bg_in, const float* __restrict__ bg_out,
    int2* __restrict__ pe, float* __restrict__ gate, int E)
{
    int pos = blockIdx.x * 256 + threadIdx.x;
    if (pos >= E) return;
    int e   = edge_list[pos];
    int src = ei[e];
    int t   = deparc[e];
    int rel = deprel[e];
    float gl = xg[(size_t)src * 4 + t];
    if (t == 0)      gl += bg_in[rel];
    else if (t == 1) gl += bg_out[rel];
    pe[pos]   = make_int2(src | (t << 20), rel);
    gate[pos] = 1.f / (1.f + __expf(-gl));
}

// ---------------- Aggregate: one wave per node --------------------------------
// Metadata for up to 64 edges loaded in parallel (lane i -> edge i), broadcast by
// shfl; row gathers (xv bf16 256B, bias fp32 512B) software-prefetched by 1.
__global__ __launch_bounds__(256) void aggregate_k(
    const unsigned short* __restrict__ xv, const int2* __restrict__ pe,
    const float* __restrict__ gate,
    const int* __restrict__ row_start, const int* __restrict__ counts,
    const float* __restrict__ b_in, const float* __restrict__ b_out,
    const unsigned short* __restrict__ xb, float* __restrict__ out, int N)
{
    int n = blockIdx.x * 4 + (threadIdx.x >> 6);
    if (n >= N) return;
    int lane = threadIdx.x & 63;

    int start = row_start[n];
    int cnt   = counts[n];
    float a0 = 0.f, a1 = 0.f;

    for (int base = 0; base < cnt; base += 64) {
        int m = min(cnt - base, 64);
        int2 mp = make_int2(0, 0);
        float mg = 0.f;
        if (lane < m) {
            mp = pe[start + base + lane];
            mg = gate[start + base + lane];
        }
        // prefetch edge 0
        int p0  = __shfl(mp.x, 0, 64);
        int rl  = __shfl(mp.y, 0, 64);
        int src = p0 & 0xFFFFF, t = p0 >> 20;
        unsigned int xx = *(const unsigned int*)(xv + (size_t)src * 512 + t * 128 + lane * 2);
        float2 bb = make_float2(0.f, 0.f);
        if (t < 2)
            bb = *(const float2*)(((t == 0) ? b_in : b_out) + (size_t)rl * DIM + lane * 2);

        for (int j = 0; j < m; ++j) {
            float g = __shfl(mg, j, 64);
            unsigned int xx_c = xx;
            float2 bb_c = bb;
            if (j + 1 < m) {  // prefetch edge j+1 before consuming j
                int p1   = __shfl(mp.x, j + 1, 64);
                int rl1  = __shfl(mp.y, j + 1, 64);
                int src1 = p1 & 0xFFFFF, t1 = p1 >> 20;
                xx = *(const unsigned int*)(xv + (size_t)src1 * 512 + t1 * 128 + lane * 2);
                bb = make_float2(0.f, 0.f);
                if (t1 < 2)
                    bb = *(const float2*)(((t1 == 0) ? b_in : b_out) + (size_t)rl1 * DIM + lane * 2);
            }
            a0 += (bf2f(xx_c & 0xffffu) + bb_c.x) * g;
            a1 += (bf2f(xx_c >> 16)     + bb_c.y) * g;
        }
    }

    unsigned int ix = *(const unsigned int*)(xb + (size_t)n * DIM + lane * 2);
    float o0 = fmaxf(a0 + bf2f(ix & 0xffffu), 0.f);
    float o1 = fmaxf(a1 + bf2f(ix >> 16), 0.f);
    *(float2*)(out + (size_t)n * DIM + lane * 2) = make_float2(o0, o1);
}

extern "C" void kernel_launch(void* const* d_in, const int* in_sizes, int n_in,
                              void* d_out, int out_size, void* d_ws, size_t ws_size,
                              hipStream_t stream)
{
    const float* inp    = (const float*)d_in[0];
    const int*   deprel = (const int*)d_in[1];
    const int*   deparc = (const int*)d_in[2];
    const int*   ei     = (const int*)d_in[3];
    const float* Vin    = (const float*)d_in[4];
    const float* b_in   = (const float*)d_in[5];
    const float* gin    = (const float*)d_in[6];
    const float* bg_in  = (const float*)d_in[7];
    const float* Vout   = (const float*)d_in[8];
    const float* b_out  = (const float*)d_in[9];
    const float* gout   = (const float*)d_in[10];
    const float* bg_out = (const float*)d_in[11];
    const float* Wself  = (const float*)d_in[12];
    const float* gself  = (const float*)d_in[13];
    const float* Wnorel = (const float*)d_in[14];
    const float* gnorel = (const float*)d_in[15];
    float*       out    = (float*)d_out;

    const int N = in_sizes[0] / DIM;   // 100000
    const int E = in_sizes[1];         // 400000

    char* ws = (char*)d_ws;
    size_t off = 0;
    auto alloc = [&](size_t bytes) -> void* {
        void* p = ws + off;
        off = (off + bytes + 255) & ~(size_t)255;
        return p;
    };
    float*          xg        = (float*)alloc((size_t)N * 4 * 4);     // 1.6 MB
    int*            counts    = (int*)alloc((size_t)N * 4);
    int*            row_start = (int*)alloc((size_t)N * 4);
    int*            cursor    = (int*)alloc((size_t)N * 4);
    int*            edge_list = (int*)alloc((size_t)E * 4);           // 1.6 MB
    int2*           pe        = (int2*)alloc((size_t)E * 8);          // 3.2 MB
    float*          gate      = (float*)alloc((size_t)E * 4);         // 1.6 MB
    int*            blocksums = (int*)alloc(128 * 4);
    unsigned short* xb        = (unsigned short*)alloc((size_t)N * DIM * 2); // 25.6 MB
    unsigned short* xv        = (unsigned short*)alloc((size_t)N * 512 * 2); // 102.4 MB

    int nb_scan = (N + 1023) / 1024;
    int ntiles  = (N + 15) / 16;
    int nb_edge = (E + 255) / 256;
    int nb_node = (N + 3) / 4;

    // CSR build
    hipMemsetAsync(counts, 0, (size_t)N * 4, stream);
    hist_k<<<nb_edge, 256, 0, stream>>>(ei, counts, E);
    scan_block_k<<<nb_scan, 256, 0, stream>>>(counts, row_start, blocksums, N);
    scan_sums_k<<<1, 128, 0, stream>>>(blocksums, nb_scan);
    scan_add_k<<<nb_scan, 256, 0, stream>>>(row_start, cursor, blocksums, N);
    scatter_k<<<nb_edge, 256, 0, stream>>>(ei, cursor, edge_list, E);

    // dense transforms
    conv_gate_k<<<nb_node, 256, 0, stream>>>(inp, gin, gout, gself, gnorel, xb, xg, N);
    gemm_xv_k<<<1280, 512, 0, stream>>>(xb, Vin, Vout, Wself, Wnorel, xv, ntiles, N);

    // per-edge payload + gate (all random reads L2-resident)
    payload_gate_k<<<nb_edge, 256, 0, stream>>>(edge_list, ei, deprel, deparc,
                                                xg, bg_in, bg_out, pe, gate, E);

    // gather + gated accumulate + residual + relu
    aggregate_k<<<nb_node, 256, 0, stream>>>(xv, pe, gate, row_start, counts,
                                             b_in, b_out, xb, out, N);
}